// Round 9
// baseline (829.670 us; speedup 1.0000x reference)
//
#include <hip/hip_runtime.h>
#include <math.h>

#define C 96
#define K 512
#define P_PER_B 110592   // 48*48*48
#define NPOS 221184      // 2 * 110592
#define BT 128           // threads per block = positions per block
#define XROW 97          // padded LDS row stride (97: lane*97%32 = lane%32, conflict-free)
#define NK 16            // prototypes per accumulator group

// ---------------------------------------------------------------------------
// Strategy (validated round 3, absmax=0): harness reference is fp32 numpy.
// Fast pass computes best/second + margin; margin < 1e-4*||x|| positions are
// re-resolved with a bit-exact numpy-fp32 emulation (refine_kernel).
//
// Round 9 restructure: r7's 4x4 LDS micro-tile costs 1 B/FLOP of LDS traffic
// = 21.8 GB = 316 us floor at 69 TB/s — r7 (336 us) was LDS-BW-bound, and
// r8's prefetch registers spilled (WRITE_SIZE 404 MB). Fix: prototypes are
// WAVE-UNIFORM -> move them to the scalar pipe (s_load_dwordx16 +
// v_fmac vD,sS,vX). Per thread: own position, x row in LDS read via
// ds_read_b128 (1 read per 64 FMAs = 0.125 B/FLOP -> LDS floor 52 us).
// acc[16] + misc ~= 40 VGPR — inside the allocator's demonstrated comfort
// zone (r7: 68 ok). No pt staging, no merge phase, one barrier total.
// ---------------------------------------------------------------------------

// Workspace: pnT[96][512] fp32 = numpy-exact normalized prototypes,
// TRANSPOSED to channel-major (192 KB). For fixed c, 16 consecutive k are
// contiguous -> s_load_dwordx16.

__global__ __launch_bounds__(256) void prep_kernel(const float* __restrict__ proto,
                                                   float* __restrict__ pnT) {
    int k = blockIdx.x * 256 + threadIdx.x;
    if (k >= K) return;
    const float* row = proto + k * C;
    // numpy pairwise_sum, n=96 <= blocksize: 8 accumulators + fixed combine
    float r[8];
#pragma unroll
    for (int j = 0; j < 8; ++j) r[j] = __fmul_rn(row[j], row[j]);
    for (int i = 8; i < C; i += 8) {
#pragma unroll
        for (int j = 0; j < 8; ++j)
            r[j] = __fadd_rn(r[j], __fmul_rn(row[i + j], row[i + j]));
    }
    float res = __fadd_rn(__fadd_rn(__fadd_rn(r[0], r[1]), __fadd_rn(r[2], r[3])),
                          __fadd_rn(__fadd_rn(r[4], r[5]), __fadd_rn(r[6], r[7])));
    float n = fmaxf(__fsqrt_rn(res), 1e-12f);
    for (int c = 0; c < C; ++c)
        pnT[(size_t)c * K + k] = __fdiv_rn(row[c], n);   // coalesced across k
}

// ---------------------------------------------------------------------------
// Fast pass: SGPR-broadcast argmax. 128 threads, one position each.
// x row staged transposed into LDS (conflict-free stride 97); prototypes
// stream through SGPRs (uniform address -> scalar loads, parallel pipe).
// ---------------------------------------------------------------------------
__global__ __launch_bounds__(BT) void sim_argmax_kernel(
        const float* __restrict__ x,
        const float* __restrict__ pnT,
        int* __restrict__ out) {
    __shared__ float xt[BT * XROW];   // 49664 B -> 3 blocks/CU

    int tid = threadIdx.x;
    int g = blockIdx.x * BT + tid;    // grid exact: g < NPOS
    int b = (g >= P_PER_B) ? 1 : 0;   // uniform per block (P_PER_B % BT == 0)
    int p = g - b * P_PER_B;
    const float* xb = x + (size_t)b * (size_t)C * P_PER_B + p;

    // Stage own x row transposed; coalesced global reads (consecutive lanes =
    // consecutive positions); LDS writes stride 97 -> conflict-free.
    // ||x||^2 computed on the fly (no extra reads).
    float n2 = 0.f;
#pragma unroll 8
    for (int c = 0; c < C; ++c) {
        float v = xb[(size_t)c * P_PER_B];
        xt[tid * XROW + c] = v;
        n2 = fmaf(v, v, n2);
    }
    __syncthreads();

    const float* xr = xt + tid * XROW;

    float best = -3.4e38f, second = -3.4e38f;
    int bestk = 0;

#pragma unroll 1
    for (int k0 = 0; k0 < K; k0 += NK) {
        float acc[NK];
#pragma unroll
        for (int j = 0; j < NK; ++j) acc[j] = 0.f;

        const float* pk = pnT + k0;   // column block [c][k0..k0+15]
#pragma unroll 2
        for (int cq = 0; cq < C / 4; ++cq) {
            float4 xv = *(const float4*)(xr + cq * 4);   // ds_read_b128
            // 64 FMAs per LDS read; proto operands are wave-uniform ->
            // s_load_dwordx16 + v_fmac vD, sS, vX.
#pragma unroll
            for (int j = 0; j < NK; ++j) {
                acc[j] = fmaf(xv.x, pk[(size_t)(cq * 4 + 0) * K + j], acc[j]);
                acc[j] = fmaf(xv.y, pk[(size_t)(cq * 4 + 1) * K + j], acc[j]);
                acc[j] = fmaf(xv.z, pk[(size_t)(cq * 4 + 2) * K + j], acc[j]);
                acc[j] = fmaf(xv.w, pk[(size_t)(cq * 4 + 3) * K + j], acc[j]);
            }
        }

#pragma unroll
        for (int j = 0; j < NK; ++j) {
            float s = acc[j];
            if (s > best) {
                second = best;
                best = s;
                bestk = k0 + j;
            } else if (s > second) {
                second = s;
            }
        }
    }

    // worst-case (fast-pass + numpy) rounding < 1.8e-5*||x||; 5x margin.
    float tau = 1e-4f * sqrtf(n2);
    out[g] = (best - second < tau) ? (bestk | (int)0x80000000) : bestk;
}

// ---------------------------------------------------------------------------
// Refine pass (validated round 3): bit-exact numpy-fp32 emulation of flagged
// positions. Thread t handles prototypes t and t+256 (reads pnT channel-
// major — same stored bits, same c-ascending order). LDS tree argmax with
// first-index tie-break.
// ---------------------------------------------------------------------------
__global__ __launch_bounds__(256) void refine_kernel(
        const float* __restrict__ x,
        const float* __restrict__ pnT,
        int* __restrict__ out) {
    __shared__ int list[256];
    __shared__ int cnt;
    __shared__ float xn[C];
    __shared__ float nrm_s;
    __shared__ float sc[256];
    __shared__ int ki[256];

    int tid = threadIdx.x;
    int g = blockIdx.x * 256 + tid;

    if (tid == 0) cnt = 0;
    __syncthreads();

    if (out[g] < 0) {
        int i = atomicAdd(&cnt, 1);
        list[i] = g;
    }
    __syncthreads();
    int n = cnt;

    for (int i = 0; i < n; ++i) {
        int gg = list[i];
        int b = (gg >= P_PER_B) ? 1 : 0;
        int p = gg - b * P_PER_B;
        const float* xb = x + (size_t)b * (size_t)C * P_PER_B + p;

        if (tid < C) xn[tid] = xb[(size_t)tid * P_PER_B];
        __syncthreads();

        // numpy: norm over non-contiguous axis -> strictly sequential fp32
        if (tid == 0) {
            float acc = __fmul_rn(xn[0], xn[0]);
            for (int c = 1; c < C; ++c)
                acc = __fadd_rn(acc, __fmul_rn(xn[c], xn[c]));
            nrm_s = fmaxf(__fsqrt_rn(acc), 1e-12f);
        }
        __syncthreads();
        if (tid < C) xn[tid] = __fdiv_rn(xn[tid], nrm_s);
        __syncthreads();

        // einsum optimize=False: sequential fp32 mul+add, c ascending, no FMA
        float s0 = 0.f, s1 = 0.f;
        for (int c = 0; c < C; ++c) {
            s0 = __fadd_rn(s0, __fmul_rn(xn[c], pnT[(size_t)c * K + tid]));
            s1 = __fadd_rn(s1, __fmul_rn(xn[c], pnT[(size_t)c * K + tid + 256]));
        }

        float bv = s0;
        int bk = tid;
        if (s1 > bv) { bv = s1; bk = tid + 256; }  // strict: lower index wins ties

        sc[tid] = bv;
        ki[tid] = bk;
        __syncthreads();

        for (int off = 128; off > 0; off >>= 1) {
            if (tid < off) {
                float ov = sc[tid + off];
                int oi = ki[tid + off];
                if (ov > sc[tid] || (ov == sc[tid] && oi < ki[tid])) {
                    sc[tid] = ov;
                    ki[tid] = oi;
                }
            }
            __syncthreads();
        }

        if (tid == 0) out[gg] = ki[0];
        __syncthreads();
    }
}

// ---------------------------------------------------------------------------
extern "C" void kernel_launch(void* const* d_in, const int* in_sizes, int n_in,
                              void* d_out, int out_size, void* d_ws, size_t ws_size,
                              hipStream_t stream) {
    const float* x = (const float*)d_in[0];      // [2,96,48,48,48] fp32
    const float* proto = (const float*)d_in[1];  // [512,96] fp32
    int* out = (int*)d_out;                      // [2,48,48,48] int32

    float* pnT = (float*)d_ws;                   // 96*512*4 = 196608 B

    prep_kernel<<<2, 256, 0, stream>>>(proto, pnT);
    sim_argmax_kernel<<<NPOS / BT, BT, 0, stream>>>(x, pnT, out);
    refine_kernel<<<NPOS / 256, 256, 0, stream>>>(x, pnT, out);
}